// Round 1
// baseline (1451.810 us; speedup 1.0000x reference)
//
#include <hip/hip_runtime.h>
#include <hip/hip_bf16.h>
#include <math.h>

#define NROWS   262144
#define BM      128
#define THREADS 512
#define LDSB    131072

using bf16x8 = __attribute__((ext_vector_type(8))) short;
using s16x4  = __attribute__((ext_vector_type(4))) short;
using f32x4  = __attribute__((ext_vector_type(4))) float;

__device__ __forceinline__ short f2bf(float f) {
  __hip_bfloat16 h = __float2bfloat16(f);
  return __builtin_bit_cast(short, h);
}
__device__ __forceinline__ float bf2f(short s) {
  __hip_bfloat16 h = __builtin_bit_cast(__hip_bfloat16, s);
  return __bfloat162float(h);
}
// XOR-swizzled byte offset into a [128][256] bf16 LDS tile (row stride 512B)
__device__ __forceinline__ int swz(int row, int col) {
  return row * 512 + ((col * 2) ^ ((row & 7) << 4));
}

__device__ __forceinline__ float red16(float p) {
  p += __shfl_xor(p, 1, 64);
  p += __shfl_xor(p, 2, 64);
  p += __shfl_xor(p, 4, 64);
  p += __shfl_xor(p, 8, 64);
  return p;
}

__device__ __forceinline__ void zero_acc(f32x4 (&acc)[8][2]) {
#pragma unroll
  for (int m = 0; m < 8; ++m)
#pragma unroll
    for (int n = 0; n < 2; ++n)
      acc[m][n] = (f32x4){0.f, 0.f, 0.f, 0.f};
}

// stage a [128][256] f32 global tile -> swizzled bf16 LDS tile
__device__ __forceinline__ void stage_tile(char* __restrict__ buf,
                                           const float* __restrict__ g, int tid) {
#pragma unroll
  for (int it = 0; it < 16; ++it) {
    int idx = it * THREADS + tid;
    int r = idx >> 6;
    int c = (idx & 63) << 2;
    float4 v = *(const float4*)(g + r * 256 + c);
    s16x4 o;
    o[0] = f2bf(v.x); o[1] = f2bf(v.y); o[2] = f2bf(v.z); o[3] = f2bf(v.w);
    *(s16x4*)(buf + swz(r, c)) = o;
  }
}

// C[128 x 32cols] += A_lds[128 x 256] @ WT[cols][K] (B pre-transposed bf16)
// wave handles cols cb..cb+31 (n=0,1), K always 256 (chunk offset koff into WT rows)
__device__ __forceinline__ void gemm256(const char* __restrict__ Abuf,
                                        const short* __restrict__ WT, int Kw,
                                        int cb, int koff, int li, int hi,
                                        f32x4 (&acc)[8][2]) {
  const short* w0 = WT + (size_t)(cb + li) * Kw + koff + hi * 8;
  const short* w1 = WT + (size_t)(cb + 16 + li) * Kw + koff + hi * 8;
#pragma unroll 2
  for (int kk = 0; kk < 256; kk += 32) {
    int ka = kk + hi * 8;
    bf16x8 b0 = *(const bf16x8*)(w0 + kk);
    bf16x8 b1 = *(const bf16x8*)(w1 + kk);
    bf16x8 a[8];
#pragma unroll
    for (int m = 0; m < 8; ++m)
      a[m] = *(const bf16x8*)(Abuf + swz(16 * m + li, ka));
#pragma unroll
    for (int m = 0; m < 8; ++m) {
      acc[m][0] = __builtin_amdgcn_mfma_f32_16x16x32_bf16(a[m], b0, acc[m][0], 0, 0, 0);
      acc[m][1] = __builtin_amdgcn_mfma_f32_16x16x32_bf16(a[m], b1, acc[m][1], 0, 0, 0);
    }
  }
}

// transpose + bf16-convert all weights into ws:
// WqT,WkT,WvT,WoT: [256][256]; W1T: [1024][256]; W2T: [256][1024]
__global__ void prep(const float* __restrict__ Wq, const float* __restrict__ Wk,
                     const float* __restrict__ Wv, const float* __restrict__ Wo,
                     const float* __restrict__ W1, const float* __restrict__ W2,
                     short* __restrict__ wt) {
  int idx = blockIdx.x * blockDim.x + threadIdx.x;  // 0..786431
  if (idx < 262144) {
    int m = idx >> 16;
    const float* W = (m == 0) ? Wq : (m == 1) ? Wk : (m == 2) ? Wv : Wo;
    int l = idx & 65535;
    int n = l >> 8, k = l & 255;
    wt[idx] = f2bf(W[k * 256 + n]);
  } else if (idx < 524288) {
    int l = idx - 262144;
    int n = l >> 8, k = l & 255;
    wt[idx] = f2bf(W1[k * 1024 + n]);
  } else {
    int l = idx - 524288;
    int n = l >> 10, k = l & 1023;
    wt[idx] = f2bf(W2[k * 256 + n]);
  }
}

__global__ __launch_bounds__(THREADS, 2)
void fused(const float* __restrict__ x, const float* __restrict__ sx,
           const float* __restrict__ dx,
           const float* __restrict__ bq, const float* __restrict__ bk,
           const float* __restrict__ bv, const float* __restrict__ bo,
           const float* __restrict__ b1, const float* __restrict__ b2,
           const float* __restrict__ g1, const float* __restrict__ be1,
           const float* __restrict__ g2, const float* __restrict__ be2,
           const short* __restrict__ wt, float* __restrict__ out) {
  extern __shared__ char sm[];
  char* Cbuf = sm;                              // 64KB: Vs-stash -> ctx -> h
  char* Tbuf = sm + 65536;                      // 64KB: A-stage / hid / LN scratch
  float* scr  = (float*)(sm + 65536);           // LN partial sums (8KB, union w/ Tbuf)
  float* scr2 = (float*)(sm + 65536 + 8192);    // LN mean/rstd (1KB)

  const short* WqT = wt;
  const short* WkT = wt + 65536;
  const short* WvT = wt + 131072;
  const short* WoT = wt + 196608;
  const short* W1T = wt + 262144;
  const short* W2T = wt + 524288;

  const int tid  = threadIdx.x;
  const int w    = tid >> 6;
  const int lane = tid & 63;
  const int li   = lane & 15;
  const int hi   = lane >> 4;
  const int cb   = w * 32;                      // wave col slice = head w
  const size_t row0 = (size_t)blockIdx.x * BM;

  const float* xt = x  + row0 * 256;
  const float* st = sx + row0 * 256;
  const float* dt = dx + row0 * 256;

  // ============ attention ============
  stage_tile(Tbuf, xt, tid);
  __syncthreads();

  f32x4 qa[8][2], ka[8][2], va[8][2];
  zero_acc(qa);
  gemm256(Tbuf, WqT, 256, cb, 0, li, hi, qa);
  {
    float bq0 = bq[cb + li], bq1 = bq[cb + 16 + li];
#pragma unroll
    for (int m = 0; m < 8; ++m)
#pragma unroll
      for (int j = 0; j < 4; ++j) { qa[m][0][j] += bq0; qa[m][1][j] += bq1; }
  }
  __syncthreads();

  stage_tile(Tbuf, st, tid);
  __syncthreads();

  zero_acc(ka);
  gemm256(Tbuf, WkT, 256, cb, 0, li, hi, ka);
  float ss[8][4];
  {
    float bk0 = bk[cb + li], bk1 = bk[cb + 16 + li];
#pragma unroll
    for (int m = 0; m < 8; ++m)
#pragma unroll
      for (int j = 0; j < 4; ++j) {
        float p = qa[m][0][j] * (ka[m][0][j] + bk0) + qa[m][1][j] * (ka[m][1][j] + bk1);
        ss[m][j] = red16(p) * 0.17677669529663687f;
      }
  }
  zero_acc(va);
  gemm256(Tbuf, WvT, 256, cb, 0, li, hi, va);   // Vs, stash raw to Cbuf (wave-private cols)
#pragma unroll
  for (int m = 0; m < 8; ++m)
#pragma unroll
    for (int n = 0; n < 2; ++n)
#pragma unroll
      for (int j = 0; j < 4; ++j)
        *(short*)(Cbuf + swz(16 * m + 4 * hi + j, cb + 16 * n + li)) = f2bf(va[m][n][j]);
  __syncthreads();

  stage_tile(Tbuf, dt, tid);
  __syncthreads();

  zero_acc(ka);
  gemm256(Tbuf, WkT, 256, cb, 0, li, hi, ka);   // Kd
  float aw[8][4];
  {
    float bk0 = bk[cb + li], bk1 = bk[cb + 16 + li];
#pragma unroll
    for (int m = 0; m < 8; ++m)
#pragma unroll
      for (int j = 0; j < 4; ++j) {
        float p = qa[m][0][j] * (ka[m][0][j] + bk0) + qa[m][1][j] * (ka[m][1][j] + bk1);
        float sd = red16(p) * 0.17677669529663687f;
        aw[m][j] = 1.f / (1.f + expf(sd - ss[m][j]));   // softmax weight for src
      }
  }
  zero_acc(va);
  gemm256(Tbuf, WvT, 256, cb, 0, li, hi, va);   // Vd
  {
    float bv0 = bv[cb + li], bv1 = bv[cb + 16 + li];
#pragma unroll
    for (int m = 0; m < 8; ++m)
#pragma unroll
      for (int j = 0; j < 4; ++j) {
        int r = 16 * m + 4 * hi + j;
        float a = aw[m][j];
#pragma unroll
        for (int n = 0; n < 2; ++n) {
          short* p = (short*)(Cbuf + swz(r, cb + 16 * n + li));
          float vs = bf2f(*p);
          float ctx = a * vs + (1.f - a) * va[m][n][j] + (n ? bv1 : bv0);
          *p = f2bf(ctx);
        }
      }
  }
  __syncthreads();

  // ============ out-proj + residual + LN1 ============
  f32x4 oa[8][2];
  zero_acc(oa);
  gemm256(Cbuf, WoT, 256, cb, 0, li, hi, oa);
  {
    float bo0 = bo[cb + li], bo1 = bo[cb + 16 + li];
#pragma unroll
    for (int m = 0; m < 8; ++m)
#pragma unroll
      for (int j = 0; j < 4; ++j) {
        int r = 16 * m + 4 * hi + j;
        float v0 = oa[m][0][j] + bo0 + xt[r * 256 + cb + li];
        float v1 = oa[m][1][j] + bo1 + xt[r * 256 + cb + 16 + li];
        oa[m][0][j] = v0; oa[m][1][j] = v1;
        float s = red16(v0 + v1);
        float q = red16(v0 * v0 + v1 * v1);
        if (li == 0) { scr[(w * 128 + r) * 2] = s; scr[(w * 128 + r) * 2 + 1] = q; }
      }
  }
  __syncthreads();
  if (tid < BM) {
    float S = 0.f, Q = 0.f;
#pragma unroll
    for (int ww = 0; ww < 8; ++ww) {
      S += scr[(ww * 128 + tid) * 2];
      Q += scr[(ww * 128 + tid) * 2 + 1];
    }
    float mean = S * (1.f / 256.f);
    float var  = Q * (1.f / 256.f) - mean * mean;
    scr2[tid * 2] = mean;
    scr2[tid * 2 + 1] = rsqrtf(var + 1e-5f);
  }
  __syncthreads();
  {
    float g10 = g1[cb + li], g11 = g1[cb + 16 + li];
    float a10 = be1[cb + li], a11 = be1[cb + 16 + li];
#pragma unroll
    for (int m = 0; m < 8; ++m)
#pragma unroll
      for (int j = 0; j < 4; ++j) {
        int r = 16 * m + 4 * hi + j;
        float mean = scr2[r * 2], rs = scr2[r * 2 + 1];
        *(short*)(Cbuf + swz(r, cb + li))      = f2bf((oa[m][0][j] - mean) * rs * g10 + a10);
        *(short*)(Cbuf + swz(r, cb + 16 + li)) = f2bf((oa[m][1][j] - mean) * rs * g11 + a11);
      }
  }
  __syncthreads();

  // ============ FFN (4 chunks of 256 hidden) ============
  f32x4 a2[8][2];
  zero_acc(a2);
#pragma unroll 1
  for (int c = 0; c < 4; ++c) {
    f32x4 a1[8][2];
    zero_acc(a1);
    gemm256(Cbuf, W1T, 256, 256 * c + cb, 0, li, hi, a1);
    {
      float b10 = b1[256 * c + cb + li], b11 = b1[256 * c + cb + 16 + li];
#pragma unroll
      for (int m = 0; m < 8; ++m)
#pragma unroll
        for (int j = 0; j < 4; ++j) {
          int r = 16 * m + 4 * hi + j;
          *(short*)(Tbuf + swz(r, cb + li))      = f2bf(fmaxf(a1[m][0][j] + b10, 0.f));
          *(short*)(Tbuf + swz(r, cb + 16 + li)) = f2bf(fmaxf(a1[m][1][j] + b11, 0.f));
        }
    }
    __syncthreads();
    gemm256(Tbuf, W2T, 1024, cb, 256 * c, li, hi, a2);
    __syncthreads();
  }

  // ============ +b2 + h residual + LN2 + store ============
  {
    float b20 = b2[cb + li], b21 = b2[cb + 16 + li];
#pragma unroll
    for (int m = 0; m < 8; ++m)
#pragma unroll
      for (int j = 0; j < 4; ++j) {
        int r = 16 * m + 4 * hi + j;
        float h0 = bf2f(*(short*)(Cbuf + swz(r, cb + li)));
        float h1 = bf2f(*(short*)(Cbuf + swz(r, cb + 16 + li)));
        float v0 = a2[m][0][j] + b20 + h0;
        float v1 = a2[m][1][j] + b21 + h1;
        a2[m][0][j] = v0; a2[m][1][j] = v1;
        float s = red16(v0 + v1);
        float q = red16(v0 * v0 + v1 * v1);
        if (li == 0) { scr[(w * 128 + r) * 2] = s; scr[(w * 128 + r) * 2 + 1] = q; }
      }
  }
  __syncthreads();
  if (tid < BM) {
    float S = 0.f, Q = 0.f;
#pragma unroll
    for (int ww = 0; ww < 8; ++ww) {
      S += scr[(ww * 128 + tid) * 2];
      Q += scr[(ww * 128 + tid) * 2 + 1];
    }
    float mean = S * (1.f / 256.f);
    float var  = Q * (1.f / 256.f) - mean * mean;
    scr2[tid * 2] = mean;
    scr2[tid * 2 + 1] = rsqrtf(var + 1e-5f);
  }
  __syncthreads();
  {
    float g20 = g2[cb + li], g21 = g2[cb + 16 + li];
    float a20 = be2[cb + li], a21 = be2[cb + 16 + li];
    float* orow = out + row0 * 256;
#pragma unroll
    for (int m = 0; m < 8; ++m)
#pragma unroll
      for (int j = 0; j < 4; ++j) {
        int r = 16 * m + 4 * hi + j;
        float mean = scr2[r * 2], rs = scr2[r * 2 + 1];
        orow[r * 256 + cb + li]      = (a2[m][0][j] - mean) * rs * g20 + a20;
        orow[r * 256 + cb + 16 + li] = (a2[m][1][j] - mean) * rs * g21 + a21;
      }
  }
}

extern "C" void kernel_launch(void* const* d_in, const int* in_sizes, int n_in,
                              void* d_out, int out_size, void* d_ws, size_t ws_size,
                              hipStream_t stream) {
  const float* x   = (const float*)d_in[0];
  const float* sx  = (const float*)d_in[1];
  const float* dx  = (const float*)d_in[2];
  const float* Wq  = (const float*)d_in[3];
  const float* bq  = (const float*)d_in[4];
  const float* Wk  = (const float*)d_in[5];
  const float* bk  = (const float*)d_in[6];
  const float* Wv  = (const float*)d_in[7];
  const float* bv  = (const float*)d_in[8];
  const float* Wo  = (const float*)d_in[9];
  const float* bo  = (const float*)d_in[10];
  const float* W1  = (const float*)d_in[11];
  const float* b1  = (const float*)d_in[12];
  const float* W2  = (const float*)d_in[13];
  const float* b2  = (const float*)d_in[14];
  const float* g1  = (const float*)d_in[15];
  const float* be1 = (const float*)d_in[16];
  const float* g2  = (const float*)d_in[17];
  const float* be2 = (const float*)d_in[18];
  short* wt = (short*)d_ws;

  prep<<<dim3(1536), dim3(512), 0, stream>>>(Wq, Wk, Wv, Wo, W1, W2, wt);
  fused<<<dim3(NROWS / BM), dim3(THREADS), LDSB, stream>>>(
      x, sx, dx, bq, bk, bv, bo, b1, b2, g1, be1, g2, be2, wt, (float*)d_out);
}

// Round 2
// 1325.454 us; speedup vs baseline: 1.0953x; 1.0953x over previous
//
#include <hip/hip_runtime.h>
#include <hip/hip_bf16.h>
#include <math.h>

#define NROWS   262144
#define BM      64
#define THREADS 512
#define LDSB    65536

using bf16x8 = __attribute__((ext_vector_type(8))) short;
using s16x4  = __attribute__((ext_vector_type(4))) short;
using f32x4  = __attribute__((ext_vector_type(4))) float;

__device__ __forceinline__ short f2bf(float f) {
  __hip_bfloat16 h = __float2bfloat16(f);
  return __builtin_bit_cast(short, h);
}
__device__ __forceinline__ float bf2f(short s) {
  __hip_bfloat16 h = __builtin_bit_cast(__hip_bfloat16, s);
  return __bfloat162float(h);
}
// XOR-swizzled byte offset into a [64][256] bf16 LDS tile (row stride 512B)
__device__ __forceinline__ int swz(int row, int col) {
  return row * 512 + ((col * 2) ^ ((row & 7) << 4));
}

__device__ __forceinline__ float red16(float p) {
  p += __shfl_xor(p, 1, 64);
  p += __shfl_xor(p, 2, 64);
  p += __shfl_xor(p, 4, 64);
  p += __shfl_xor(p, 8, 64);
  return p;
}

__device__ __forceinline__ void zero_acc(f32x4 (&acc)[4][2]) {
#pragma unroll
  for (int m = 0; m < 4; ++m)
#pragma unroll
    for (int n = 0; n < 2; ++n)
      acc[m][n] = (f32x4){0.f, 0.f, 0.f, 0.f};
}

// stage a [64][256] f32 global tile -> swizzled bf16 LDS tile
__device__ __forceinline__ void stage_tile(char* __restrict__ buf,
                                           const float* __restrict__ g, int tid) {
#pragma unroll
  for (int it = 0; it < 8; ++it) {
    int idx = it * THREADS + tid;
    int r = idx >> 6;
    int c = (idx & 63) << 2;
    float4 v = *(const float4*)(g + r * 256 + c);
    s16x4 o;
    o[0] = f2bf(v.x); o[1] = f2bf(v.y); o[2] = f2bf(v.z); o[3] = f2bf(v.w);
    *(s16x4*)(buf + swz(r, c)) = o;
  }
}

// C[64 x 32cols] += A_lds[64 x 256] @ WT[cols][K] (B pre-transposed bf16)
__device__ __forceinline__ void gemm256(const char* __restrict__ Abuf,
                                        const short* __restrict__ WT, int Kw,
                                        int cb, int koff, int li, int hi,
                                        f32x4 (&acc)[4][2]) {
  const short* w0 = WT + (size_t)(cb + li) * Kw + koff + hi * 8;
  const short* w1 = WT + (size_t)(cb + 16 + li) * Kw + koff + hi * 8;
#pragma unroll 4
  for (int kk = 0; kk < 256; kk += 32) {
    int ka = kk + hi * 8;
    bf16x8 b0 = *(const bf16x8*)(w0 + kk);
    bf16x8 b1 = *(const bf16x8*)(w1 + kk);
    bf16x8 a[4];
#pragma unroll
    for (int m = 0; m < 4; ++m)
      a[m] = *(const bf16x8*)(Abuf + swz(16 * m + li, ka));
#pragma unroll
    for (int m = 0; m < 4; ++m) {
      acc[m][0] = __builtin_amdgcn_mfma_f32_16x16x32_bf16(a[m], b0, acc[m][0], 0, 0, 0);
      acc[m][1] = __builtin_amdgcn_mfma_f32_16x16x32_bf16(a[m], b1, acc[m][1], 0, 0, 0);
    }
  }
}

// transpose + bf16-convert all weights into ws:
// WqT,WkT,WvT,WoT: [256][256]; W1T: [1024][256]; W2T: [256][1024]
__global__ void prep(const float* __restrict__ Wq, const float* __restrict__ Wk,
                     const float* __restrict__ Wv, const float* __restrict__ Wo,
                     const float* __restrict__ W1, const float* __restrict__ W2,
                     short* __restrict__ wt) {
  int idx = blockIdx.x * blockDim.x + threadIdx.x;  // 0..786431
  if (idx < 262144) {
    int m = idx >> 16;
    const float* W = (m == 0) ? Wq : (m == 1) ? Wk : (m == 2) ? Wv : Wo;
    int l = idx & 65535;
    int n = l >> 8, k = l & 255;
    wt[idx] = f2bf(W[k * 256 + n]);
  } else if (idx < 524288) {
    int l = idx - 262144;
    int n = l >> 8, k = l & 255;
    wt[idx] = f2bf(W1[k * 1024 + n]);
  } else {
    int l = idx - 524288;
    int n = l >> 10, k = l & 1023;
    wt[idx] = f2bf(W2[k * 256 + n]);
  }
}

__global__ __launch_bounds__(THREADS, 4)
void fused(const float* __restrict__ x, const float* __restrict__ sx,
           const float* __restrict__ dx,
           const float* __restrict__ bq, const float* __restrict__ bk,
           const float* __restrict__ bv, const float* __restrict__ bo,
           const float* __restrict__ b1, const float* __restrict__ b2,
           const float* __restrict__ g1, const float* __restrict__ be1,
           const float* __restrict__ g2, const float* __restrict__ be2,
           const short* __restrict__ wt, float* __restrict__ out) {
  extern __shared__ char sm[];
  char* Cbuf = sm;                              // 32KB: Vs-stash -> ctx -> h -> out-stage
  char* Tbuf = sm + 32768;                      // 32KB: A-stage / hid / LN scratch
  float* scr  = (float*)(sm + 32768);           // LN partial sums (4KB, union w/ Tbuf)
  float* scr2 = (float*)(sm + 32768 + 4096);    // LN mean/rstd (512B)

  const short* WqT = wt;
  const short* WkT = wt + 65536;
  const short* WvT = wt + 131072;
  const short* WoT = wt + 196608;
  const short* W1T = wt + 262144;
  const short* W2T = wt + 524288;

  const int tid  = threadIdx.x;
  const int w    = tid >> 6;
  const int lane = tid & 63;
  const int li   = lane & 15;
  const int hi   = lane >> 4;
  const int cb   = w * 32;                      // wave col slice = head w
  const size_t row0 = (size_t)blockIdx.x * BM;

  const float* xt = x  + row0 * 256;
  const float* st = sx + row0 * 256;
  const float* dt = dx + row0 * 256;

  // ============ attention ============
  stage_tile(Tbuf, xt, tid);
  __syncthreads();

  f32x4 qa[4][2], ka[4][2], va[4][2];
  zero_acc(qa);
  gemm256(Tbuf, WqT, 256, cb, 0, li, hi, qa);
  {
    float bq0 = bq[cb + li], bq1 = bq[cb + 16 + li];
#pragma unroll
    for (int m = 0; m < 4; ++m)
#pragma unroll
      for (int j = 0; j < 4; ++j) { qa[m][0][j] += bq0; qa[m][1][j] += bq1; }
  }
  __syncthreads();

  stage_tile(Tbuf, st, tid);
  __syncthreads();

  zero_acc(ka);
  gemm256(Tbuf, WkT, 256, cb, 0, li, hi, ka);
  float ss[4][4];
  {
    float bk0 = bk[cb + li], bk1 = bk[cb + 16 + li];
#pragma unroll
    for (int m = 0; m < 4; ++m)
#pragma unroll
      for (int j = 0; j < 4; ++j) {
        float p = qa[m][0][j] * (ka[m][0][j] + bk0) + qa[m][1][j] * (ka[m][1][j] + bk1);
        ss[m][j] = red16(p) * 0.17677669529663687f;
      }
  }
  zero_acc(va);
  gemm256(Tbuf, WvT, 256, cb, 0, li, hi, va);   // Vs, stash raw to Cbuf (wave-private cols)
#pragma unroll
  for (int m = 0; m < 4; ++m)
#pragma unroll
    for (int n = 0; n < 2; ++n)
#pragma unroll
      for (int j = 0; j < 4; ++j)
        *(short*)(Cbuf + swz(16 * m + 4 * hi + j, cb + 16 * n + li)) = f2bf(va[m][n][j]);
  __syncthreads();

  stage_tile(Tbuf, dt, tid);
  __syncthreads();

  zero_acc(ka);
  gemm256(Tbuf, WkT, 256, cb, 0, li, hi, ka);   // Kd
  float aw[4][4];
  {
    float bk0 = bk[cb + li], bk1 = bk[cb + 16 + li];
#pragma unroll
    for (int m = 0; m < 4; ++m)
#pragma unroll
      for (int j = 0; j < 4; ++j) {
        float p = qa[m][0][j] * (ka[m][0][j] + bk0) + qa[m][1][j] * (ka[m][1][j] + bk1);
        float sd = red16(p) * 0.17677669529663687f;
        aw[m][j] = 1.f / (1.f + expf(sd - ss[m][j]));   // softmax weight for src
      }
  }
  zero_acc(va);
  gemm256(Tbuf, WvT, 256, cb, 0, li, hi, va);   // Vd
  {
    float bv0 = bv[cb + li], bv1 = bv[cb + 16 + li];
#pragma unroll
    for (int m = 0; m < 4; ++m)
#pragma unroll
      for (int j = 0; j < 4; ++j) {
        int r = 16 * m + 4 * hi + j;
        float a = aw[m][j];
#pragma unroll
        for (int n = 0; n < 2; ++n) {
          short* p = (short*)(Cbuf + swz(r, cb + 16 * n + li));
          float vs = bf2f(*p);
          float ctx = a * vs + (1.f - a) * va[m][n][j] + (n ? bv1 : bv0);
          *p = f2bf(ctx);
        }
      }
  }
  __syncthreads();

  // ============ out-proj + residual + LN1 ============
  f32x4 oa[4][2];
  zero_acc(oa);
  gemm256(Cbuf, WoT, 256, cb, 0, li, hi, oa);
  {
    float bo0 = bo[cb + li], bo1 = bo[cb + 16 + li];
#pragma unroll
    for (int m = 0; m < 4; ++m)
#pragma unroll
      for (int j = 0; j < 4; ++j) {
        int r = 16 * m + 4 * hi + j;
        float v0 = oa[m][0][j] + bo0 + xt[r * 256 + cb + li];
        float v1 = oa[m][1][j] + bo1 + xt[r * 256 + cb + 16 + li];
        oa[m][0][j] = v0; oa[m][1][j] = v1;
        float s = red16(v0 + v1);
        float q = red16(v0 * v0 + v1 * v1);
        if (li == 0) { scr[(w * 64 + r) * 2] = s; scr[(w * 64 + r) * 2 + 1] = q; }
      }
  }
  __syncthreads();
  if (tid < BM) {
    float S = 0.f, Q = 0.f;
#pragma unroll
    for (int ww = 0; ww < 8; ++ww) {
      S += scr[(ww * 64 + tid) * 2];
      Q += scr[(ww * 64 + tid) * 2 + 1];
    }
    float mean = S * (1.f / 256.f);
    float var  = Q * (1.f / 256.f) - mean * mean;
    scr2[tid * 2] = mean;
    scr2[tid * 2 + 1] = rsqrtf(var + 1e-5f);
  }
  __syncthreads();
  {
    float g10 = g1[cb + li], g11 = g1[cb + 16 + li];
    float a10 = be1[cb + li], a11 = be1[cb + 16 + li];
#pragma unroll
    for (int m = 0; m < 4; ++m)
#pragma unroll
      for (int j = 0; j < 4; ++j) {
        int r = 16 * m + 4 * hi + j;
        float mean = scr2[r * 2], rs = scr2[r * 2 + 1];
        *(short*)(Cbuf + swz(r, cb + li))      = f2bf((oa[m][0][j] - mean) * rs * g10 + a10);
        *(short*)(Cbuf + swz(r, cb + 16 + li)) = f2bf((oa[m][1][j] - mean) * rs * g11 + a11);
      }
  }
  __syncthreads();

  // ============ FFN (4 chunks of 256 hidden) ============
  f32x4 a2[4][2];
  zero_acc(a2);
#pragma unroll 1
  for (int c = 0; c < 4; ++c) {
    f32x4 a1[4][2];
    zero_acc(a1);
    gemm256(Cbuf, W1T, 256, 256 * c + cb, 0, li, hi, a1);
    {
      float b10 = b1[256 * c + cb + li], b11 = b1[256 * c + cb + 16 + li];
#pragma unroll
      for (int m = 0; m < 4; ++m)
#pragma unroll
        for (int j = 0; j < 4; ++j) {
          int r = 16 * m + 4 * hi + j;
          *(short*)(Tbuf + swz(r, cb + li))      = f2bf(fmaxf(a1[m][0][j] + b10, 0.f));
          *(short*)(Tbuf + swz(r, cb + 16 + li)) = f2bf(fmaxf(a1[m][1][j] + b11, 0.f));
        }
    }
    __syncthreads();
    gemm256(Tbuf, W2T, 1024, cb, 256 * c, li, hi, a2);
    __syncthreads();
  }

  // ============ +b2 + h residual + LN2 ============
  {
    float b20 = b2[cb + li], b21 = b2[cb + 16 + li];
#pragma unroll
    for (int m = 0; m < 4; ++m)
#pragma unroll
      for (int j = 0; j < 4; ++j) {
        int r = 16 * m + 4 * hi + j;
        float h0 = bf2f(*(short*)(Cbuf + swz(r, cb + li)));
        float h1 = bf2f(*(short*)(Cbuf + swz(r, cb + 16 + li)));
        float v0 = a2[m][0][j] + b20 + h0;
        float v1 = a2[m][1][j] + b21 + h1;
        a2[m][0][j] = v0; a2[m][1][j] = v1;
        float s = red16(v0 + v1);
        float q = red16(v0 * v0 + v1 * v1);
        if (li == 0) { scr[(w * 64 + r) * 2] = s; scr[(w * 64 + r) * 2 + 1] = q; }
      }
  }
  __syncthreads();
  if (tid < BM) {
    float S = 0.f, Q = 0.f;
#pragma unroll
    for (int ww = 0; ww < 8; ++ww) {
      S += scr[(ww * 64 + tid) * 2];
      Q += scr[(ww * 64 + tid) * 2 + 1];
    }
    float mean = S * (1.f / 256.f);
    float var  = Q * (1.f / 256.f) - mean * mean;
    scr2[tid * 2] = mean;
    scr2[tid * 2 + 1] = rsqrtf(var + 1e-5f);
  }
  __syncthreads();

  // ============ LN2 apply + coalesced store via LDS f32 stage (2 halves) ============
  {
    float g20 = g2[cb + li], g21 = g2[cb + 16 + li];
    float a20 = be2[cb + li], a21 = be2[cb + 16 + li];
    float* orow = out + row0 * 256;
#pragma unroll 1
    for (int hf = 0; hf < 2; ++hf) {
#pragma unroll
      for (int m2 = 0; m2 < 2; ++m2) {
        int m = 2 * hf + m2;
#pragma unroll
        for (int j = 0; j < 4; ++j) {
          int r = 16 * m + 4 * hi + j;
          float mean = scr2[r * 2], rs = scr2[r * 2 + 1];
          int rr = r - 32 * hf;
          float v0 = (a2[m][0][j] - mean) * rs * g20 + a20;
          float v1 = (a2[m][1][j] - mean) * rs * g21 + a21;
          *(float*)(Cbuf + rr * 1024 + (((cb + li) * 4) ^ ((rr & 7) << 4)))      = v0;
          *(float*)(Cbuf + rr * 1024 + (((cb + 16 + li) * 4) ^ ((rr & 7) << 4))) = v1;
        }
      }
      __syncthreads();
#pragma unroll
      for (int t = 0; t < 4; ++t) {
        int idx = t * THREADS + tid;      // 0..2047 float4 slots
        int r = idx >> 6, c4 = idx & 63;
        f32x4 v = *(f32x4*)(Cbuf + r * 1024 + ((c4 * 16) ^ ((r & 7) << 4)));
        *(f32x4*)(orow + (hf * 32 + r) * 256 + c4 * 4) = v;
      }
      __syncthreads();
    }
  }
}

extern "C" void kernel_launch(void* const* d_in, const int* in_sizes, int n_in,
                              void* d_out, int out_size, void* d_ws, size_t ws_size,
                              hipStream_t stream) {
  const float* x   = (const float*)d_in[0];
  const float* sx  = (const float*)d_in[1];
  const float* dx  = (const float*)d_in[2];
  const float* Wq  = (const float*)d_in[3];
  const float* bq  = (const float*)d_in[4];
  const float* Wk  = (const float*)d_in[5];
  const float* bk  = (const float*)d_in[6];
  const float* Wv  = (const float*)d_in[7];
  const float* bv  = (const float*)d_in[8];
  const float* Wo  = (const float*)d_in[9];
  const float* bo  = (const float*)d_in[10];
  const float* W1  = (const float*)d_in[11];
  const float* b1  = (const float*)d_in[12];
  const float* W2  = (const float*)d_in[13];
  const float* b2  = (const float*)d_in[14];
  const float* g1  = (const float*)d_in[15];
  const float* be1 = (const float*)d_in[16];
  const float* g2  = (const float*)d_in[17];
  const float* be2 = (const float*)d_in[18];
  short* wt = (short*)d_ws;

  prep<<<dim3(1536), dim3(512), 0, stream>>>(Wq, Wk, Wv, Wo, W1, W2, wt);
  fused<<<dim3(NROWS / BM), dim3(THREADS), LDSB, stream>>>(
      x, sx, dx, bq, bk, bv, bo, b1, b2, g1, be1, g2, be2, wt, (float*)d_out);
}

// Round 3
// 1139.412 us; speedup vs baseline: 1.2742x; 1.1633x over previous
//
#include <hip/hip_runtime.h>
#include <hip/hip_bf16.h>
#include <math.h>

#define NROWS   262144
#define BM      64
#define THREADS 512
#define LDSB    65536

using bf16x8 = __attribute__((ext_vector_type(8))) short;
using s16x4  = __attribute__((ext_vector_type(4))) short;
using f32x4  = __attribute__((ext_vector_type(4))) float;

__device__ __forceinline__ short f2bf(float f) {
  __hip_bfloat16 h = __float2bfloat16(f);
  return __builtin_bit_cast(short, h);
}
__device__ __forceinline__ float bf2f(short s) {
  __hip_bfloat16 h = __builtin_bit_cast(__hip_bfloat16, s);
  return __bfloat162float(h);
}
// XOR-swizzled byte offset into a [64][256] bf16 LDS tile (row stride 512B)
__device__ __forceinline__ int swz(int row, int col) {
  return row * 512 + ((col * 2) ^ ((row & 7) << 4));
}

__device__ __forceinline__ float red16(float p) {
  p += __shfl_xor(p, 1, 64);
  p += __shfl_xor(p, 2, 64);
  p += __shfl_xor(p, 4, 64);
  p += __shfl_xor(p, 8, 64);
  return p;
}

__device__ __forceinline__ void zero_acc(f32x4 (&acc)[4][2]) {
#pragma unroll
  for (int m = 0; m < 4; ++m)
#pragma unroll
    for (int n = 0; n < 2; ++n)
      acc[m][n] = (f32x4){0.f, 0.f, 0.f, 0.f};
}

// stage a [64][256] f32 global tile -> swizzled bf16 LDS tile (2 loads in flight)
__device__ __forceinline__ void stage_tile(char* __restrict__ buf,
                                           const float* __restrict__ g, int tid) {
#pragma unroll 2
  for (int it = 0; it < 8; ++it) {
    int idx = it * THREADS + tid;
    int r = idx >> 6;
    int c = (idx & 63) << 2;
    float4 v = *(const float4*)(g + r * 256 + c);
    s16x4 o;
    o[0] = f2bf(v.x); o[1] = f2bf(v.y); o[2] = f2bf(v.z); o[3] = f2bf(v.w);
    *(s16x4*)(buf + swz(r, c)) = o;
  }
}

// C[64 x 32cols] += A_lds[64 x 256] @ WT[cols][K] (B pre-transposed bf16)
__device__ __forceinline__ void gemm256(const char* __restrict__ Abuf,
                                        const short* __restrict__ WT, int Kw,
                                        int cb, int koff, int li, int hi,
                                        f32x4 (&acc)[4][2]) {
  const short* w0 = WT + (size_t)(cb + li) * Kw + koff + hi * 8;
  const short* w1 = WT + (size_t)(cb + 16 + li) * Kw + koff + hi * 8;
#pragma unroll 2
  for (int kk = 0; kk < 256; kk += 32) {
    int ka = kk + hi * 8;
    bf16x8 b0 = *(const bf16x8*)(w0 + kk);
    bf16x8 b1 = *(const bf16x8*)(w1 + kk);
    bf16x8 a[4];
#pragma unroll
    for (int m = 0; m < 4; ++m)
      a[m] = *(const bf16x8*)(Abuf + swz(16 * m + li, ka));
#pragma unroll
    for (int m = 0; m < 4; ++m) {
      acc[m][0] = __builtin_amdgcn_mfma_f32_16x16x32_bf16(a[m], b0, acc[m][0], 0, 0, 0);
      acc[m][1] = __builtin_amdgcn_mfma_f32_16x16x32_bf16(a[m], b1, acc[m][1], 0, 0, 0);
    }
  }
}

// transpose + bf16-convert all weights into ws:
// WqT,WkT,WvT,WoT: [256][256]; W1T: [1024][256]; W2T: [256][1024]
__global__ void prep(const float* __restrict__ Wq, const float* __restrict__ Wk,
                     const float* __restrict__ Wv, const float* __restrict__ Wo,
                     const float* __restrict__ W1, const float* __restrict__ W2,
                     short* __restrict__ wt) {
  int idx = blockIdx.x * blockDim.x + threadIdx.x;  // 0..786431
  if (idx < 262144) {
    int m = idx >> 16;
    const float* W = (m == 0) ? Wq : (m == 1) ? Wk : (m == 2) ? Wv : Wo;
    int l = idx & 65535;
    int n = l >> 8, k = l & 255;
    wt[idx] = f2bf(W[k * 256 + n]);
  } else if (idx < 524288) {
    int l = idx - 262144;
    int n = l >> 8, k = l & 255;
    wt[idx] = f2bf(W1[k * 1024 + n]);
  } else {
    int l = idx - 524288;
    int n = l >> 10, k = l & 1023;
    wt[idx] = f2bf(W2[k * 256 + n]);
  }
}

__global__ __attribute__((amdgpu_waves_per_eu(4, 4))) __launch_bounds__(THREADS)
void fused(const float* __restrict__ x, const float* __restrict__ sx,
           const float* __restrict__ dx,
           const float* __restrict__ bq,
           const float* __restrict__ bv, const float* __restrict__ bo,
           const float* __restrict__ b1, const float* __restrict__ b2,
           const float* __restrict__ g1, const float* __restrict__ be1,
           const float* __restrict__ g2, const float* __restrict__ be2,
           const short* __restrict__ wt, float* __restrict__ out) {
  extern __shared__ char sm[];
  char* Tbuf = sm;             // x tile -> src tile -> LN1 scratch -> hid tile -> out stage
  char* Cbuf = sm + 32768;     // dst tile -> ctx -> h -> LN2 scratch
  float* scrT  = (float*)Tbuf;
  float* scr2T = (float*)(Tbuf + 4096);
  float* scrC  = (float*)Cbuf;
  float* scr2C = (float*)(Cbuf + 4096);

  const short* WqT = wt;
  const short* WkT = wt + 65536;
  const short* WvT = wt + 131072;
  const short* WoT = wt + 196608;
  const short* W1T = wt + 262144;
  const short* W2T = wt + 524288;

  const int tid  = threadIdx.x;
  const int w    = tid >> 6;
  const int lane = tid & 63;
  const int li   = lane & 15;
  const int hi   = lane >> 4;
  const int cb   = w * 32;                      // wave col slice = head w
  const size_t row0 = (size_t)blockIdx.x * BM;

  const float* xt = x  + row0 * 256;
  const float* st = sx + row0 * 256;
  const float* dt = dx + row0 * 256;

  // ---- P0: stage x ----
  stage_tile(Tbuf, xt, tid);
  __syncthreads();

  // ---- P1: Q gemm (Tbuf) || stage dst -> Cbuf ----
  f32x4 qa[4][2];
  zero_acc(qa);
  gemm256(Tbuf, WqT, 256, cb, 0, li, hi, qa);
  stage_tile(Cbuf, dt, tid);
  {
    const float scl = 0.17677669529663687f;   // 1/sqrt(32)
    float bq0 = bq[cb + li], bq1 = bq[cb + 16 + li];
#pragma unroll
    for (int m = 0; m < 4; ++m)
#pragma unroll
      for (int j = 0; j < 4; ++j) {
        qa[m][0][j] = (qa[m][0][j] + bq0) * scl;
        qa[m][1][j] = (qa[m][1][j] + bq1) * scl;
      }
  }
  __syncthreads();

  // ---- P2: K_dst gemm (Cbuf) -> pd || stage src -> Tbuf ----
  float pd[4][4];
  {
    f32x4 ka[4][2];
    zero_acc(ka);
    gemm256(Cbuf, WkT, 256, cb, 0, li, hi, ka);
    stage_tile(Tbuf, st, tid);
#pragma unroll
    for (int m = 0; m < 4; ++m)
#pragma unroll
      for (int j = 0; j < 4; ++j)
        pd[m][j] = red16(qa[m][0][j] * ka[m][0][j] + qa[m][1][j] * ka[m][1][j]);
  }
  __syncthreads();

  // ---- P3: K_src gemm (Tbuf) -> aw; V_src (Tbuf); V_dst (Cbuf); combine ----
  float aw[4][4];
  {
    f32x4 ka[4][2];
    zero_acc(ka);
    gemm256(Tbuf, WkT, 256, cb, 0, li, hi, ka);
#pragma unroll
    for (int m = 0; m < 4; ++m)
#pragma unroll
      for (int j = 0; j < 4; ++j) {
        float ps = red16(qa[m][0][j] * ka[m][0][j] + qa[m][1][j] * ka[m][1][j]);
        aw[m][j] = 1.f / (1.f + expf(pd[m][j] - ps));   // weight on V_src
      }
  }
  f32x4 vs[4][2];
  zero_acc(vs);
  gemm256(Tbuf, WvT, 256, cb, 0, li, hi, vs);
  {
    f32x4 vd[4][2];
    zero_acc(vd);
    gemm256(Cbuf, WvT, 256, cb, 0, li, hi, vd);
    float bv0 = bv[cb + li], bv1 = bv[cb + 16 + li];
#pragma unroll
    for (int m = 0; m < 4; ++m)
#pragma unroll
      for (int j = 0; j < 4; ++j) {
        float a = aw[m][j];
        vs[m][0][j] = a * vs[m][0][j] + (1.f - a) * vd[m][0][j] + bv0;
        vs[m][1][j] = a * vs[m][1][j] + (1.f - a) * vd[m][1][j] + bv1;
      }
  }
  __syncthreads();

  // ---- P4: ctx -> Cbuf (bf16, swizzled) ----
#pragma unroll
  for (int m = 0; m < 4; ++m)
#pragma unroll
    for (int n = 0; n < 2; ++n)
#pragma unroll
      for (int j = 0; j < 4; ++j)
        *(short*)(Cbuf + swz(16 * m + 4 * hi + j, cb + 16 * n + li)) = f2bf(vs[m][n][j]);
  __syncthreads();

  // ---- P5: O-proj gemm (Cbuf) + bo + x residual + LN1 partials ----
  f32x4 oa[4][2];
  zero_acc(oa);
  gemm256(Cbuf, WoT, 256, cb, 0, li, hi, oa);
  {
    float bo0 = bo[cb + li], bo1 = bo[cb + 16 + li];
#pragma unroll
    for (int m = 0; m < 4; ++m)
#pragma unroll
      for (int j = 0; j < 4; ++j) {
        int r = 16 * m + 4 * hi + j;
        float v0 = oa[m][0][j] + bo0 + xt[r * 256 + cb + li];
        float v1 = oa[m][1][j] + bo1 + xt[r * 256 + cb + 16 + li];
        oa[m][0][j] = v0; oa[m][1][j] = v1;
        float s = red16(v0 + v1);
        float q = red16(v0 * v0 + v1 * v1);
        if (li == 0) { scrT[(w * 64 + r) * 2] = s; scrT[(w * 64 + r) * 2 + 1] = q; }
      }
  }
  __syncthreads();
  if (tid < BM) {
    float S = 0.f, Q = 0.f;
#pragma unroll
    for (int ww = 0; ww < 8; ++ww) {
      S += scrT[(ww * 64 + tid) * 2];
      Q += scrT[(ww * 64 + tid) * 2 + 1];
    }
    float mean = S * (1.f / 256.f);
    float var  = Q * (1.f / 256.f) - mean * mean;
    scr2T[tid * 2] = mean;
    scr2T[tid * 2 + 1] = rsqrtf(var + 1e-5f);
  }
  __syncthreads();
  {
    float g10 = g1[cb + li], g11 = g1[cb + 16 + li];
    float a10 = be1[cb + li], a11 = be1[cb + 16 + li];
#pragma unroll
    for (int m = 0; m < 4; ++m)
#pragma unroll
      for (int j = 0; j < 4; ++j) {
        int r = 16 * m + 4 * hi + j;
        float mean = scr2T[r * 2], rs = scr2T[r * 2 + 1];
        *(short*)(Cbuf + swz(r, cb + li))      = f2bf((oa[m][0][j] - mean) * rs * g10 + a10);
        *(short*)(Cbuf + swz(r, cb + 16 + li)) = f2bf((oa[m][1][j] - mean) * rs * g11 + a11);
      }
  }
  __syncthreads();

  // ---- FFN: 4 chunks of 256 hidden; h in Cbuf, hid chunk in Tbuf ----
  f32x4 a2[4][2];
  zero_acc(a2);
#pragma unroll 1
  for (int c = 0; c < 4; ++c) {
    f32x4 a1[4][2];
    zero_acc(a1);
    gemm256(Cbuf, W1T, 256, 256 * c + cb, 0, li, hi, a1);
    {
      float b10 = b1[256 * c + cb + li], b11 = b1[256 * c + cb + 16 + li];
#pragma unroll
      for (int m = 0; m < 4; ++m)
#pragma unroll
        for (int j = 0; j < 4; ++j) {
          int r = 16 * m + 4 * hi + j;
          *(short*)(Tbuf + swz(r, cb + li))      = f2bf(fmaxf(a1[m][0][j] + b10, 0.f));
          *(short*)(Tbuf + swz(r, cb + 16 + li)) = f2bf(fmaxf(a1[m][1][j] + b11, 0.f));
        }
    }
    __syncthreads();
    gemm256(Tbuf, W2T, 1024, cb, 256 * c, li, hi, a2);
    __syncthreads();
  }

  // ---- +b2 + h residual (reads Cbuf) ----
  {
    float b20 = b2[cb + li], b21 = b2[cb + 16 + li];
#pragma unroll
    for (int m = 0; m < 4; ++m)
#pragma unroll
      for (int j = 0; j < 4; ++j) {
        int r = 16 * m + 4 * hi + j;
        a2[m][0][j] += b20 + bf2f(*(short*)(Cbuf + swz(r, cb + li)));
        a2[m][1][j] += b21 + bf2f(*(short*)(Cbuf + swz(r, cb + 16 + li)));
      }
  }
  __syncthreads();   // all h reads done before scrC overwrites Cbuf

  // ---- LN2 partials -> scrC ----
#pragma unroll
  for (int m = 0; m < 4; ++m)
#pragma unroll
    for (int j = 0; j < 4; ++j) {
      int r = 16 * m + 4 * hi + j;
      float v0 = a2[m][0][j], v1 = a2[m][1][j];
      float s = red16(v0 + v1);
      float q = red16(v0 * v0 + v1 * v1);
      if (li == 0) { scrC[(w * 64 + r) * 2] = s; scrC[(w * 64 + r) * 2 + 1] = q; }
    }
  __syncthreads();
  if (tid < BM) {
    float S = 0.f, Q = 0.f;
#pragma unroll
    for (int ww = 0; ww < 8; ++ww) {
      S += scrC[(ww * 64 + tid) * 2];
      Q += scrC[(ww * 64 + tid) * 2 + 1];
    }
    float mean = S * (1.f / 256.f);
    float var  = Q * (1.f / 256.f) - mean * mean;
    scr2C[tid * 2] = mean;
    scr2C[tid * 2 + 1] = rsqrtf(var + 1e-5f);
  }
  __syncthreads();

  // ---- LN2 apply + coalesced store via Tbuf f32 stage (2 halves of 32 rows) ----
  {
    float g20 = g2[cb + li], g21 = g2[cb + 16 + li];
    float a20 = be2[cb + li], a21 = be2[cb + 16 + li];
    float* orow = out + row0 * 256;
#pragma unroll 1
    for (int hf = 0; hf < 2; ++hf) {
#pragma unroll
      for (int m2 = 0; m2 < 2; ++m2) {
        int m = 2 * hf + m2;
#pragma unroll
        for (int j = 0; j < 4; ++j) {
          int r = 16 * m + 4 * hi + j;
          float mean = scr2C[r * 2], rs = scr2C[r * 2 + 1];
          int rr = r - 32 * hf;
          *(float*)(Tbuf + rr * 1024 + (((cb + li) * 4) ^ ((rr & 7) << 4)))
              = (a2[m][0][j] - mean) * rs * g20 + a20;
          *(float*)(Tbuf + rr * 1024 + (((cb + 16 + li) * 4) ^ ((rr & 7) << 4)))
              = (a2[m][1][j] - mean) * rs * g21 + a21;
        }
      }
      __syncthreads();
#pragma unroll
      for (int t = 0; t < 4; ++t) {
        int idx = t * THREADS + tid;      // 0..2047 float4 slots
        int r = idx >> 6, c4 = idx & 63;
        f32x4 v = *(f32x4*)(Tbuf + r * 1024 + ((c4 * 16) ^ ((r & 7) << 4)));
        *(f32x4*)(orow + (hf * 32 + r) * 256 + c4 * 4) = v;
      }
      __syncthreads();
    }
  }
}

extern "C" void kernel_launch(void* const* d_in, const int* in_sizes, int n_in,
                              void* d_out, int out_size, void* d_ws, size_t ws_size,
                              hipStream_t stream) {
  const float* x   = (const float*)d_in[0];
  const float* sx  = (const float*)d_in[1];
  const float* dx  = (const float*)d_in[2];
  const float* Wq  = (const float*)d_in[3];
  const float* bq  = (const float*)d_in[4];
  const float* Wk  = (const float*)d_in[5];
  const float* Wv  = (const float*)d_in[7];
  const float* bv  = (const float*)d_in[8];
  const float* Wo  = (const float*)d_in[9];
  const float* bo  = (const float*)d_in[10];
  const float* W1  = (const float*)d_in[11];
  const float* b1  = (const float*)d_in[12];
  const float* W2  = (const float*)d_in[13];
  const float* b2  = (const float*)d_in[14];
  const float* g1  = (const float*)d_in[15];
  const float* be1 = (const float*)d_in[16];
  const float* g2  = (const float*)d_in[17];
  const float* be2 = (const float*)d_in[18];
  short* wt = (short*)d_ws;

  prep<<<dim3(1536), dim3(512), 0, stream>>>(Wq, Wk, Wv, Wo, W1, W2, wt);
  fused<<<dim3(NROWS / BM), dim3(THREADS), LDSB, stream>>>(
      x, sx, dx, bq, bv, bo, b1, b2, g1, be1, g2, be2, wt, (float*)d_out);
}